// Round 7
// baseline (173.815 us; speedup 1.0000x reference)
//
#include <hip/hip_runtime.h>
#include <hip/hip_bf16.h>
#include <math.h>

// MHSA, fp32 I/O, bf16 MFMA internally.
// R18: launch fusion — k_cvt + k_tcvt_qkv + k_tcvt merged into one k_prep
// (blockIdx-range dispatch, block-uniform branches). 6 kernels -> 4:
// dispatch-gap accounting showed ~60us of inter-launch bubbles (sum of
// dispatch durations ~109us vs 171us wall). Compute kernels (k_qkv, k_attn,
// k_merge) are byte-identical to R17 (counted-vmcnt pipelines).

#define B_  8
#define P_  1024
#define T_  768
#define H_  12
#define DV  64
#define F3  2304   // 3*H*DV
#define HD  768    // H*DV
#define PSTR 72    // P^T q-row stride in elems: 144 B, bank-rotating

typedef float  f32x4  __attribute__((ext_vector_type(4)));
typedef __bf16 bf16x4 __attribute__((ext_vector_type(4)));
typedef __bf16 bf16x8 __attribute__((ext_vector_type(8)));

#if defined(__has_builtin)
#if __has_builtin(__builtin_amdgcn_exp2f)
#define EX2(x) __builtin_amdgcn_exp2f(x)
#endif
#endif
#ifndef EX2
#define EX2(x) exp2f(x)
#endif

__device__ __forceinline__ void gload16(const void* g, void* l) {
    __builtin_amdgcn_global_load_lds((const __attribute__((address_space(1))) void*)g,
                                     (__attribute__((address_space(3))) void*)l,
                                     16, 0, 0);
}

// ---- fused preprocessing: X cvt (768 blk) | W_qkv T (1728 blk) | W_m T (576) -
__global__ __launch_bounds__(256) void k_prep(const float* __restrict__ x,
                                              __bf16* __restrict__ Xb,
                                              const float* __restrict__ wqkv,
                                              __bf16* __restrict__ WqT,
                                              const float* __restrict__ wm,
                                              __bf16* __restrict__ WmT) {
    int bid = blockIdx.x;
    int tid = threadIdx.x;

    if (bid < 768) {
        // ---- X fp32 -> bf16, XCD-affine (original k_cvt) ----
        int xcd = bid & 7;
        int seq = bid >> 3;
        int strip = (seq / 12) * 8 + xcd;
        int sub   = seq % 12;
        size_t base = (size_t)strip * (128 * T_) + (size_t)sub * (128 * T_ / 12);
        const float4* s4 = (const float4*)(x + base);
        bf16x4*       d4 = (bf16x4*)(Xb + base);
#pragma unroll
        for (int i = 0; i < 8; i++) {
            float4 v = s4[i * 256 + tid];
            bf16x4 o = { (__bf16)v.x, (__bf16)v.y, (__bf16)v.z, (__bf16)v.w };
            d4[i * 256 + tid] = o;
        }
        return;
    }

    __shared__ __bf16 tile[32][33];
    int tx = tid & 31, ty = tid >> 5;

    if (bid < 768 + 1728) {
        // ---- W_qkv fp32 (768x2304) -> bf16 (2304x768) T + column sort ----
        int u  = bid - 768;
        int bx = u % 72, by = u / 72;
        int n = bx * 32 + tx;
        int r = n / 768, idx = n - r * 768;
        int f = (idx >> 6) * 192 + (idx & 63) * 3 + r;
        int t0 = by * 32;
#pragma unroll
        for (int j = 0; j < 32; j += 8)
            tile[ty + j][tx] = (__bf16)wqkv[(size_t)(t0 + ty + j) * F3 + f];
        __syncthreads();
#pragma unroll
        for (int j = 0; j < 32; j += 8)
            WqT[(size_t)(bx * 32 + ty + j) * T_ + t0 + tx] = tile[tx][ty + j];
    } else {
        // ---- W_merge fp32 (768x768) -> bf16 transpose ----
        int u  = bid - 768 - 1728;
        int bx = u % 24, by = u / 24;
        int xx = bx * 32 + tx;
        int y  = by * 32 + ty;
#pragma unroll
        for (int j = 0; j < 32; j += 8)
            tile[ty + j][tx] = (__bf16)wm[(size_t)(y + j) * HD + xx];
        __syncthreads();
        int x2 = by * 32 + tx;
        int y2 = bx * 32 + ty;
#pragma unroll
        for (int j = 0; j < 32; j += 8)
            WmT[(size_t)(y2 + j) * T_ + x2] = tile[tx][ty + j];
    }
}

// ---- shared BK=64 swizzled mainloop, R17: counted-vmcnt double-buffer -------
// Per iter: issue(next tile) -> vmcnt(8) [own prev-tile loads done, 8 newest
// in flight] -> s_barrier [union complete] -> compute -> s_barrier [reads
// done before next overwrite]. No full vmcnt drain in the main loop.
#define GEMM64_MAINLOOP(Aptr, Btptr, brow, bcol, LD)                             \
    int tid  = threadIdx.x;                                                      \
    int lane = tid & 63, wave = tid >> 6;                                        \
    int l16  = lane & 15, quad = lane >> 4;                                      \
    int wm = (wave >> 1) * 64, wn = (wave & 1) * 64;                             \
    int bro = tid >> 3, bq = tid & 7;                                            \
    f32x4 acc[4][4];                                                             \
    _Pragma("unroll") for (int i = 0; i < 4; i++)                                \
        _Pragma("unroll") for (int j = 0; j < 4; j++)                            \
            acc[i][j] = (f32x4){0.f, 0.f, 0.f, 0.f};                             \
    _Pragma("unroll") for (int it = 0; it < 4; it++) {                           \
        int n = it * 32 + bro;                                                   \
        int gp = bq ^ (n & 7);                                                   \
        gload16((Aptr) + (size_t)((brow) * 128 + n) * (LD) + gp * 8,             \
                LDSb + it * 2048 + tid * 8);                                     \
        gload16((Btptr) + (size_t)((bcol) * 128 + n) * (LD) + gp * 8,            \
                LDSb + 8192 + it * 2048 + tid * 8);                              \
    }                                                                            \
    for (int k0 = 0; k0 < (LD); k0 += 64) {                                      \
        int cur = (k0 >> 6) & 1;                                                 \
        __bf16* As = LDSb + cur * 16384;                                         \
        __bf16* Bs = As + 8192;                                                  \
        if (k0 + 64 < (LD)) {                                                    \
            __bf16* Ad = LDSb + (cur ^ 1) * 16384;                               \
            _Pragma("unroll") for (int it = 0; it < 4; it++) {                   \
                int n = it * 32 + bro;                                           \
                int gp = bq ^ (n & 7);                                           \
                gload16((Aptr) + (size_t)((brow) * 128 + n) * (LD) + k0 + 64 + gp * 8, \
                        Ad + it * 2048 + tid * 8);                               \
                gload16((Btptr) + (size_t)((bcol) * 128 + n) * (LD) + k0 + 64 + gp * 8, \
                        Ad + 8192 + it * 2048 + tid * 8);                        \
            }                                                                    \
            asm volatile("s_waitcnt vmcnt(8)" ::: "memory");                     \
        } else {                                                                 \
            asm volatile("s_waitcnt vmcnt(0)" ::: "memory");                     \
        }                                                                        \
        __builtin_amdgcn_s_barrier();                                            \
        _Pragma("unroll") for (int ks = 0; ks < 2; ks++) {                       \
            bf16x8 af[4], bfr[4];                                                \
            _Pragma("unroll") for (int i = 0; i < 4; i++) {                      \
                int r = wm + i * 16 + l16;                                       \
                af[i] = *(const bf16x8*)&As[r * 64 + (((ks * 4 + quad) ^ (r & 7)) << 3)]; \
            }                                                                    \
            _Pragma("unroll") for (int j = 0; j < 4; j++) {                      \
                int r = wn + j * 16 + l16;                                       \
                bfr[j] = *(const bf16x8*)&Bs[r * 64 + (((ks * 4 + quad) ^ (r & 7)) << 3)]; \
            }                                                                    \
            _Pragma("unroll") for (int i = 0; i < 4; i++)                        \
                _Pragma("unroll") for (int j = 0; j < 4; j++)                    \
                    acc[i][j] = __builtin_amdgcn_mfma_f32_16x16x32_bf16(         \
                        af[i], bfr[j], acc[i][j], 0, 0, 0);                      \
        }                                                                        \
        __builtin_amdgcn_s_barrier();                                            \
    }

// ---------------- QKV GEMM (R17: counted vmcnt + chunked dispatch) -----------
__global__ __launch_bounds__(256, 2) void k_qkv(const __bf16* __restrict__ Xb,
                                                const __bf16* __restrict__ Wt,
                                                __bf16* __restrict__ Q,
                                                __bf16* __restrict__ K,
                                                __bf16* __restrict__ Vt) {
    __shared__ __align__(16) __bf16 LDSb[2 * 2 * 128 * 64];   // 64 KB, dbuf

    int bid  = blockIdx.x;
    int xcd  = bid & 7;
    int seq  = bid >> 3;            // 0..143 per xcd-label
    // chunked: 3 chunks of 6 bcols (== QKV regions) x 8 brow-groups.
    // per-XCD L2 working set: W chunk 1.2 MB + X panels 1.5 MB < 4 MB.
    int chunk = seq / 48;
    int rem   = seq - chunk * 48;
    int brow  = (rem / 6) * 8 + xcd;
    int bcol  = chunk * 6 + (rem % 6);

    GEMM64_MAINLOOP(Xb, Wt, brow, bcol, T_)

    int region = chunk;
    int b  = brow >> 3;
    int p0 = (brow & 7) * 128;

    if (region < 2) {
        __bf16* D = region == 0 ? Q : K;
        // Q pre-scaled by 1/8 * log2(e): attn does raw exp2(s)
        float sc = region == 0 ? 0.1803368801f : 1.0f;
#pragma unroll
        for (int j = 0; j < 4; j++) {
            int idx = (bcol - region * 6) * 128 + wn + j * 16 + l16;
            int h = idx >> 6, v = idx & 63;
            __bf16* Dh = D + ((size_t)(b * H_ + h) * P_) * DV + v;
#pragma unroll
            for (int i = 0; i < 4; i++)
#pragma unroll
                for (int r = 0; r < 4; r++)
                    Dh[(size_t)(p0 + wm + i * 16 + quad * 4 + r) * DV] =
                        (__bf16)(acc[i][j][r] * sc);
        }
    } else {
        __syncthreads();
#pragma unroll
        for (int j = 0; j < 4; j++) {
            int n_loc = wn + j * 16 + l16;
#pragma unroll
            for (int i = 0; i < 4; i++)
#pragma unroll
            for (int r = 0; r < 4; r++) {
                int m_loc = wm + i * 16 + quad * 4 + r;
                int phys  = (m_loc >> 3) ^ (n_loc & 15);
                LDSb[n_loc * 128 + phys * 8 + (m_loc & 7)] = (__bf16)acc[i][j][r];
            }
        }
        __syncthreads();
        int n_loc = tid >> 1, halfm = tid & 1;
        int idx = (bcol - 12) * 128 + n_loc;
        int h = idx >> 6, v = idx & 63;
        __bf16* Dh = Vt + ((size_t)(b * H_ + h) * DV + v) * P_ + p0 + halfm * 64;
#pragma unroll
        for (int i = 0; i < 8; i++) {
            int chunk2 = halfm * 8 + i;
            int phys   = chunk2 ^ (n_loc & 15);
            bf16x8 val = *(const bf16x8*)&LDSb[n_loc * 128 + phys * 8];
            *(bf16x8*)(Dh + i * 8) = val;
        }
    }
}

// ---------------- merge GEMM (R17: counted vmcnt) ----------------------------
__global__ __launch_bounds__(256, 2) void k_merge(const __bf16* __restrict__ O,
                                                  const __bf16* __restrict__ Wt,
                                                  float* __restrict__ out) {
    __shared__ __align__(16) __bf16 LDSb[2 * 2 * 128 * 64];   // 64 KB, dbuf

    int bid  = blockIdx.x;
    int xcd  = bid & 7;
    int seq  = bid >> 3;
    int brow = (seq / 6) * 8 + xcd;
    int bcol = seq % 6;

    GEMM64_MAINLOOP(O, Wt, brow, bcol, HD)

#pragma unroll
    for (int i = 0; i < 4; i++)
#pragma unroll
        for (int j = 0; j < 4; j++) {
            int col = bcol * 128 + wn + j * 16 + l16;
#pragma unroll
            for (int r = 0; r < 4; r++) {
                size_t row = (size_t)(brow * 128 + wm + i * 16 + quad * 4 + r);
                out[row * HD + col] = acc[i][j][r];
            }
        }
}

// ------- attention R17: counted-vmcnt K/V pipeline + 2 q-groups/wave ---------
__global__ __launch_bounds__(256, 3) void k_attn(const __bf16* __restrict__ Q,
                                                 const __bf16* __restrict__ Kb,
                                                 const __bf16* __restrict__ Vt,
                                                 __bf16* __restrict__ O) {
    __shared__ __align__(16) __bf16 KV[2][8192];         // [buf][K 4096 | V 4096]
    __shared__ __align__(16) __bf16 Pb[4][2][16 * PSTR]; // per-wave, per-group

    int tid  = threadIdx.x;
    int lane = tid & 63, wave = tid >> 6;
    int l16  = lane & 15, quad = lane >> 4;

    int bid = blockIdx.x;
    int xcd = bid & 7;
    int seq = bid >> 3;              // 0..95
    int bh  = xcd * 12 + (seq % 12); // 12 heads per XCD: K/V stays in its L2
    int qt  = seq / 12;              // 0..7, 128 q-rows per block
    int b   = bh / H_, h = bh % H_;

    const __bf16* Qb  = Q  + (size_t)bh * P_ * DV;
    const __bf16* Kbh = Kb + (size_t)bh * P_ * DV;
    const __bf16* Vbh = Vt + (size_t)bh * DV * P_;
    int m0 = qt * 128 + wave * 32;   // 2 groups: rows m0..m0+15, m0+16..m0+31

    bf16x8 a00 = *(const bf16x8*)(Qb + (size_t)(m0 + l16) * DV + quad * 8);
    bf16x8 a01 = *(const bf16x8*)(Qb + (size_t)(m0 + l16) * DV + 32 + quad * 8);
    bf16x8 a10 = *(const bf16x8*)(Qb + (size_t)(m0 + 16 + l16) * DV + quad * 8);
    bf16x8 a11 = *(const bf16x8*)(Qb + (size_t)(m0 + 16 + l16) * DV + 32 + quad * 8);

    int l8 = lane >> 3, q8 = lane & 7;

    bf16x8 ones;
#pragma unroll
    for (int i = 0; i < 8; i++) ones[i] = (__bf16)1.0f;

    __bf16* Pw0 = &Pb[wave][0][0];
    __bf16* Pw1 = &Pb[wave][1][0];
    f32x4 facc0 = {0.f,0.f,0.f,0.f}, facc1 = {0.f,0.f,0.f,0.f};
    f32x4 oacc0[4] = {{0.f,0.f,0.f,0.f},{0.f,0.f,0.f,0.f},{0.f,0.f,0.f,0.f},{0.f,0.f,0.f,0.f}};
    f32x4 oacc1[4] = {{0.f,0.f,0.f,0.f},{0.f,0.f,0.f,0.f},{0.f,0.f,0.f,0.f},{0.f,0.f,0.f,0.f}};
    int swq = l16 & 7;

    // prologue: stage tile 0 into KV[0]
#pragma unroll
    for (int i = 0; i < 2; i++) {
        int t8 = wave * 2 + i;
        int r  = t8 * 8 + l8;
        int j  = q8 ^ (r & 7);
        gload16(Kbh + (size_t)r * DV + j * 8, &KV[0][t8 * 512 + lane * 8]);
        gload16(Vbh + (size_t)r * P_ + j * 8, &KV[0][4096 + t8 * 512 + lane * 8]);
    }

    for (int t = 0; t < 16; t++) {
        int cur = t & 1;
        const __bf16* Ks = &KV[cur][0];
        const __bf16* Vs = &KV[cur][4096];

        // prefetch tile t+1 into the other buffer; counted wait leaves the
        // 4 newest loads in flight across the barrier
        if (t < 15) {
            __bf16* Kd = &KV[cur ^ 1][0];
            int c = (t + 1) * 64;
#pragma unroll
            for (int i = 0; i < 2; i++) {
                int t8 = wave * 2 + i;
                int r  = t8 * 8 + l8;
                int j  = q8 ^ (r & 7);
                gload16(Kbh + (size_t)(c + r) * DV + j * 8, Kd + t8 * 512 + lane * 8);
                gload16(Vbh + (size_t)r * P_ + c + j * 8,  Kd + 4096 + t8 * 512 + lane * 8);
            }
            asm volatile("s_waitcnt vmcnt(4)" ::: "memory");
        } else {
            asm volatile("s_waitcnt vmcnt(0)" ::: "memory");
        }
        __builtin_amdgcn_s_barrier();

        // ---- S^T = K Q^T for both q-groups ----
        f32x4 s0[4], s1[4];
#pragma unroll
        for (int ct = 0; ct < 4; ct++) {
            int R = ct * 16 + l16;
            bf16x8 b0 = *(const bf16x8*)&Ks[R * 64 + ((quad ^ swq) * 8)];
            bf16x8 b1 = *(const bf16x8*)&Ks[R * 64 + (((4 + quad) ^ swq) * 8)];
            f32x4 z0 = {0.f, 0.f, 0.f, 0.f};
            z0 = __builtin_amdgcn_mfma_f32_16x16x32_bf16(b0, a00, z0, 0, 0, 0);
            z0 = __builtin_amdgcn_mfma_f32_16x16x32_bf16(b1, a01, z0, 0, 0, 0);
            s0[ct] = z0;
            f32x4 z1 = {0.f, 0.f, 0.f, 0.f};
            z1 = __builtin_amdgcn_mfma_f32_16x16x32_bf16(b0, a10, z1, 0, 0, 0);
            z1 = __builtin_amdgcn_mfma_f32_16x16x32_bf16(b1, a11, z1, 0, 0, 0);
            s1[ct] = z1;
        }

        // ---- P^T: raw exp2 (Q pre-scaled to log2 domain), b64 writes ----
#pragma unroll
        for (int ct = 0; ct < 4; ct++) {
            bf16x4 pk0, pk1;
#pragma unroll
            for (int r = 0; r < 4; r++) {
                pk0[r] = (__bf16)EX2(s0[ct][r]);
                pk1[r] = (__bf16)EX2(s1[ct][r]);
            }
            *(bf16x4*)&Pw0[l16 * PSTR + ct * 16 + quad * 4] = pk0;
            *(bf16x4*)&Pw1[l16 * PSTR + ct * 16 + quad * 4] = pk1;
        }

        // ---- O^T += V_tile * P^T ; row sums via ones-MFMA ----
#pragma unroll
        for (int ks = 0; ks < 2; ks++) {
            bf16x8 pf0 = *(const bf16x8*)&Pw0[l16 * PSTR + ks * 32 + quad * 8];
            bf16x8 pf1 = *(const bf16x8*)&Pw1[l16 * PSTR + ks * 32 + quad * 8];
            facc0 = __builtin_amdgcn_mfma_f32_16x16x32_bf16(ones, pf0, facc0, 0, 0, 0);
            facc1 = __builtin_amdgcn_mfma_f32_16x16x32_bf16(ones, pf1, facc1, 0, 0, 0);
#pragma unroll
            for (int nt = 0; nt < 4; nt++) {
                int R = nt * 16 + l16;
                bf16x8 av = *(const bf16x8*)&Vs[R * 64 + (((ks * 4 + quad) ^ swq) * 8)];
                oacc0[nt] = __builtin_amdgcn_mfma_f32_16x16x32_bf16(av, pf0, oacc0[nt], 0, 0, 0);
                oacc1[nt] = __builtin_amdgcn_mfma_f32_16x16x32_bf16(av, pf1, oacc1[nt], 0, 0, 0);
            }
        }
        __builtin_amdgcn_s_barrier();
    }

    float inv0 = 1.0f / facc0[0];
    float inv1 = 1.0f / facc1[0];

    {
        int p = m0 + l16;
        __bf16* Orow = O + ((size_t)b * P_ + p) * HD + h * DV;
#pragma unroll
        for (int nt = 0; nt < 4; nt++) {
            bf16x4 o4;
#pragma unroll
            for (int r = 0; r < 4; r++) o4[r] = (__bf16)(oacc0[nt][r] * inv0);
            *(bf16x4*)&Orow[nt * 16 + quad * 4] = o4;
        }
    }
    {
        int p = m0 + 16 + l16;
        __bf16* Orow = O + ((size_t)b * P_ + p) * HD + h * DV;
#pragma unroll
        for (int nt = 0; nt < 4; nt++) {
            bf16x4 o4;
#pragma unroll
            for (int r = 0; r < 4; r++) o4[r] = (__bf16)(oacc1[nt][r] * inv1);
            *(bf16x4*)&Orow[nt * 16 + quad * 4] = o4;
        }
    }
}

extern "C" void kernel_launch(void* const* d_in, const int* in_sizes, int n_in,
                              void* d_out, int out_size, void* d_ws, size_t ws_size,
                              hipStream_t stream) {
    const float* x      = (const float*)d_in[0];
    const float* wqkv   = (const float*)d_in[1];
    const float* wmerge = (const float*)d_in[2];

    char* w = (char*)d_ws;
    __bf16* Xb  = (__bf16*)w;  w += (size_t)B_ * P_ * T_ * 2;
    __bf16* WqT = (__bf16*)w;  w += (size_t)F3 * T_ * 2;
    __bf16* WmT = (__bf16*)w;  w += (size_t)HD * T_ * 2;
    __bf16* Q   = (__bf16*)w;  w += (size_t)B_ * H_ * P_ * DV * 2;
    __bf16* K   = (__bf16*)w;  w += (size_t)B_ * H_ * P_ * DV * 2;
    __bf16* Vt  = (__bf16*)w;  w += (size_t)B_ * H_ * P_ * DV * 2;
    __bf16* O   = (__bf16*)w;

    hipLaunchKernelGGL(k_prep, dim3(768 + 1728 + 576), dim3(256), 0, stream,
                       x, Xb, wqkv, WqT, wmerge, WmT);

    hipLaunchKernelGGL(k_qkv, dim3((B_ * P_ / 128) * (F3 / 128)), dim3(256), 0, stream,
                       Xb, WqT, Q, K, Vt);

    hipLaunchKernelGGL(k_attn, dim3(B_ * H_ * (P_ / 128)), dim3(256), 0, stream,
                       Q, K, Vt, O);

    hipLaunchKernelGGL(k_merge, dim3((B_ * P_ / 128) * (HD / 128)), dim3(256), 0, stream,
                       O, WmT, (float*)d_out);
}

// Round 9
// 169.169 us; speedup vs baseline: 1.0275x; 1.0275x over previous
//
#include <hip/hip_runtime.h>
#include <hip/hip_bf16.h>
#include <math.h>

// MHSA, fp32 I/O, bf16 MFMA internally.
// R20 (= R19 resubmit; bench failure matched the Round-3 infra signature and
// the epilogue audit — bounds, swizzle bijectivity, barrier hazards — found
// no fault).
// R19: k_qkv Q/K epilogue de-scatter — stage the 128x128 output tile in LDS
// ([m][n-swizzled], scale folded into the write) and store 8 coalesced b128
// per thread, mirroring the existing V-path transpose. Replaces 64 scalar
// 2B global stores/thread at 128B stride (64-line scatter per wave inst).
// Everything else identical to R18 (counted-vmcnt pipelines, fused k_prep).

#define B_  8
#define P_  1024
#define T_  768
#define H_  12
#define DV  64
#define F3  2304   // 3*H*DV
#define HD  768    // H*DV
#define PSTR 72    // P^T q-row stride in elems: 144 B, bank-rotating

typedef float  f32x4  __attribute__((ext_vector_type(4)));
typedef __bf16 bf16x4 __attribute__((ext_vector_type(4)));
typedef __bf16 bf16x8 __attribute__((ext_vector_type(8)));

#if defined(__has_builtin)
#if __has_builtin(__builtin_amdgcn_exp2f)
#define EX2(x) __builtin_amdgcn_exp2f(x)
#endif
#endif
#ifndef EX2
#define EX2(x) exp2f(x)
#endif

__device__ __forceinline__ void gload16(const void* g, void* l) {
    __builtin_amdgcn_global_load_lds((const __attribute__((address_space(1))) void*)g,
                                     (__attribute__((address_space(3))) void*)l,
                                     16, 0, 0);
}

// ---- fused preprocessing: X cvt (768 blk) | W_qkv T (1728 blk) | W_m T (576) -
__global__ __launch_bounds__(256) void k_prep(const float* __restrict__ x,
                                              __bf16* __restrict__ Xb,
                                              const float* __restrict__ wqkv,
                                              __bf16* __restrict__ WqT,
                                              const float* __restrict__ wm,
                                              __bf16* __restrict__ WmT) {
    int bid = blockIdx.x;
    int tid = threadIdx.x;

    if (bid < 768) {
        // ---- X fp32 -> bf16, XCD-affine (original k_cvt) ----
        int xcd = bid & 7;
        int seq = bid >> 3;
        int strip = (seq / 12) * 8 + xcd;
        int sub   = seq % 12;
        size_t base = (size_t)strip * (128 * T_) + (size_t)sub * (128 * T_ / 12);
        const float4* s4 = (const float4*)(x + base);
        bf16x4*       d4 = (bf16x4*)(Xb + base);
#pragma unroll
        for (int i = 0; i < 8; i++) {
            float4 v = s4[i * 256 + tid];
            bf16x4 o = { (__bf16)v.x, (__bf16)v.y, (__bf16)v.z, (__bf16)v.w };
            d4[i * 256 + tid] = o;
        }
        return;
    }

    __shared__ __bf16 tile[32][33];
    int tx = tid & 31, ty = tid >> 5;

    if (bid < 768 + 1728) {
        // ---- W_qkv fp32 (768x2304) -> bf16 (2304x768) T + column sort ----
        int u  = bid - 768;
        int bx = u % 72, by = u / 72;
        int n = bx * 32 + tx;
        int r = n / 768, idx = n - r * 768;
        int f = (idx >> 6) * 192 + (idx & 63) * 3 + r;
        int t0 = by * 32;
#pragma unroll
        for (int j = 0; j < 32; j += 8)
            tile[ty + j][tx] = (__bf16)wqkv[(size_t)(t0 + ty + j) * F3 + f];
        __syncthreads();
#pragma unroll
        for (int j = 0; j < 32; j += 8)
            WqT[(size_t)(bx * 32 + ty + j) * T_ + t0 + tx] = tile[tx][ty + j];
    } else {
        // ---- W_merge fp32 (768x768) -> bf16 transpose ----
        int u  = bid - 768 - 1728;
        int bx = u % 24, by = u / 24;
        int xx = bx * 32 + tx;
        int y  = by * 32 + ty;
#pragma unroll
        for (int j = 0; j < 32; j += 8)
            tile[ty + j][tx] = (__bf16)wm[(size_t)(y + j) * HD + xx];
        __syncthreads();
        int x2 = by * 32 + tx;
        int y2 = bx * 32 + ty;
#pragma unroll
        for (int j = 0; j < 32; j += 8)
            WmT[(size_t)(y2 + j) * T_ + x2] = tile[tx][ty + j];
    }
}

// ---- shared BK=64 swizzled mainloop, R17: counted-vmcnt double-buffer -------
#define GEMM64_MAINLOOP(Aptr, Btptr, brow, bcol, LD)                             \
    int tid  = threadIdx.x;                                                      \
    int lane = tid & 63, wave = tid >> 6;                                        \
    int l16  = lane & 15, quad = lane >> 4;                                      \
    int wm = (wave >> 1) * 64, wn = (wave & 1) * 64;                             \
    int bro = tid >> 3, bq = tid & 7;                                            \
    f32x4 acc[4][4];                                                             \
    _Pragma("unroll") for (int i = 0; i < 4; i++)                                \
        _Pragma("unroll") for (int j = 0; j < 4; j++)                            \
            acc[i][j] = (f32x4){0.f, 0.f, 0.f, 0.f};                             \
    _Pragma("unroll") for (int it = 0; it < 4; it++) {                           \
        int n = it * 32 + bro;                                                   \
        int gp = bq ^ (n & 7);                                                   \
        gload16((Aptr) + (size_t)((brow) * 128 + n) * (LD) + gp * 8,             \
                LDSb + it * 2048 + tid * 8);                                     \
        gload16((Btptr) + (size_t)((bcol) * 128 + n) * (LD) + gp * 8,            \
                LDSb + 8192 + it * 2048 + tid * 8);                              \
    }                                                                            \
    for (int k0 = 0; k0 < (LD); k0 += 64) {                                      \
        int cur = (k0 >> 6) & 1;                                                 \
        __bf16* As = LDSb + cur * 16384;                                         \
        __bf16* Bs = As + 8192;                                                  \
        if (k0 + 64 < (LD)) {                                                    \
            __bf16* Ad = LDSb + (cur ^ 1) * 16384;                               \
            _Pragma("unroll") for (int it = 0; it < 4; it++) {                   \
                int n = it * 32 + bro;                                           \
                int gp = bq ^ (n & 7);                                           \
                gload16((Aptr) + (size_t)((brow) * 128 + n) * (LD) + k0 + 64 + gp * 8, \
                        Ad + it * 2048 + tid * 8);                               \
                gload16((Btptr) + (size_t)((bcol) * 128 + n) * (LD) + k0 + 64 + gp * 8, \
                        Ad + 8192 + it * 2048 + tid * 8);                        \
            }                                                                    \
            asm volatile("s_waitcnt vmcnt(8)" ::: "memory");                     \
        } else {                                                                 \
            asm volatile("s_waitcnt vmcnt(0)" ::: "memory");                     \
        }                                                                        \
        __builtin_amdgcn_s_barrier();                                            \
        _Pragma("unroll") for (int ks = 0; ks < 2; ks++) {                       \
            bf16x8 af[4], bfr[4];                                                \
            _Pragma("unroll") for (int i = 0; i < 4; i++) {                      \
                int r = wm + i * 16 + l16;                                       \
                af[i] = *(const bf16x8*)&As[r * 64 + (((ks * 4 + quad) ^ (r & 7)) << 3)]; \
            }                                                                    \
            _Pragma("unroll") for (int j = 0; j < 4; j++) {                      \
                int r = wn + j * 16 + l16;                                       \
                bfr[j] = *(const bf16x8*)&Bs[r * 64 + (((ks * 4 + quad) ^ (r & 7)) << 3)]; \
            }                                                                    \
            _Pragma("unroll") for (int i = 0; i < 4; i++)                        \
                _Pragma("unroll") for (int j = 0; j < 4; j++)                    \
                    acc[i][j] = __builtin_amdgcn_mfma_f32_16x16x32_bf16(         \
                        af[i], bfr[j], acc[i][j], 0, 0, 0);                      \
        }                                                                        \
        __builtin_amdgcn_s_barrier();                                            \
    }

// ---------------- QKV GEMM (R19: coalesced Q/K epilogue) ---------------------
__global__ __launch_bounds__(256, 2) void k_qkv(const __bf16* __restrict__ Xb,
                                                const __bf16* __restrict__ Wt,
                                                __bf16* __restrict__ Q,
                                                __bf16* __restrict__ K,
                                                __bf16* __restrict__ Vt) {
    __shared__ __align__(16) __bf16 LDSb[2 * 2 * 128 * 64];   // 64 KB, dbuf

    int bid  = blockIdx.x;
    int xcd  = bid & 7;
    int seq  = bid >> 3;            // 0..143 per xcd-label
    // chunked: 3 chunks of 6 bcols (== QKV regions) x 8 brow-groups.
    int chunk = seq / 48;
    int rem   = seq - chunk * 48;
    int brow  = (rem / 6) * 8 + xcd;
    int bcol  = chunk * 6 + (rem % 6);

    GEMM64_MAINLOOP(Xb, Wt, brow, bcol, T_)

    int region = chunk;
    int b  = brow >> 3;
    int p0 = (brow & 7) * 128;
    int bcl = bcol - region * 6;    // 0..5 within region

    if (region < 2) {
        // ---- Q/K: LDS transpose-stage, then coalesced b128 stores ----
        __bf16* D = region == 0 ? Q : K;
        // Q pre-scaled by 1/8 * log2(e): attn does raw exp2(s)
        float sc = region == 0 ? 0.1803368801f : 1.0f;
        __syncthreads();
        // stage: LDSb[m][phys(n)*8 + (n&7)], phys = (n>>3) ^ (m&15)
#pragma unroll
        for (int i = 0; i < 4; i++) {
            int m_loc = wm + i * 16 + quad * 4;
#pragma unroll
            for (int j = 0; j < 4; j++) {
                int n_loc = wn + j * 16 + l16;
#pragma unroll
                for (int r = 0; r < 4; r++) {
                    int m = m_loc + r;
                    int phys = (n_loc >> 3) ^ (m & 15);
                    LDSb[m * 128 + phys * 8 + (n_loc & 7)] =
                        (__bf16)(acc[i][j][r] * sc);
                }
            }
        }
        __syncthreads();
        // read 8 consecutive n per b128, store coalesced into Q/K
        int m_loc = tid >> 1;           // 0..127 (p within tile)
        int halfn = tid & 1;            // n half: chunks 0..7 / 8..15
        size_t prow = (size_t)(p0 + m_loc);
#pragma unroll
        for (int i = 0; i < 8; i++) {
            int ch   = halfn * 8 + i;           // n-chunk: n = ch*8..ch*8+7
            int phys = ch ^ (m_loc & 15);
            bf16x8 val = *(const bf16x8*)&LDSb[m_loc * 128 + phys * 8];
            int f = bcl * 128 + ch * 8;
            int h = f >> 6, v = f & 63;
            __bf16* Dh = D + ((size_t)(b * H_ + h) * P_ + prow) * DV + v;
            *(bf16x8*)Dh = val;
        }
    } else {
        __syncthreads();
#pragma unroll
        for (int j = 0; j < 4; j++) {
            int n_loc = wn + j * 16 + l16;
#pragma unroll
            for (int i = 0; i < 4; i++)
#pragma unroll
            for (int r = 0; r < 4; r++) {
                int m_loc = wm + i * 16 + quad * 4 + r;
                int phys  = (m_loc >> 3) ^ (n_loc & 15);
                LDSb[n_loc * 128 + phys * 8 + (m_loc & 7)] = (__bf16)acc[i][j][r];
            }
        }
        __syncthreads();
        int n_loc = tid >> 1, halfm = tid & 1;
        int idx = bcl * 128 + n_loc;
        int h = idx >> 6, v = idx & 63;
        __bf16* Dh = Vt + ((size_t)(b * H_ + h) * DV + v) * P_ + p0 + halfm * 64;
#pragma unroll
        for (int i = 0; i < 8; i++) {
            int chunk2 = halfm * 8 + i;
            int phys   = chunk2 ^ (n_loc & 15);
            bf16x8 val = *(const bf16x8*)&LDSb[n_loc * 128 + phys * 8];
            *(bf16x8*)(Dh + i * 8) = val;
        }
    }
}

// ---------------- merge GEMM (R17: counted vmcnt) ----------------------------
__global__ __launch_bounds__(256, 2) void k_merge(const __bf16* __restrict__ O,
                                                  const __bf16* __restrict__ Wt,
                                                  float* __restrict__ out) {
    __shared__ __align__(16) __bf16 LDSb[2 * 2 * 128 * 64];   // 64 KB, dbuf

    int bid  = blockIdx.x;
    int xcd  = bid & 7;
    int seq  = bid >> 3;
    int brow = (seq / 6) * 8 + xcd;
    int bcol = seq % 6;

    GEMM64_MAINLOOP(O, Wt, brow, bcol, HD)

#pragma unroll
    for (int i = 0; i < 4; i++)
#pragma unroll
        for (int j = 0; j < 4; j++) {
            int col = bcol * 128 + wn + j * 16 + l16;
#pragma unroll
            for (int r = 0; r < 4; r++) {
                size_t row = (size_t)(brow * 128 + wm + i * 16 + quad * 4 + r);
                out[row * HD + col] = acc[i][j][r];
            }
        }
}

// ------- attention R17: counted-vmcnt K/V pipeline + 2 q-groups/wave ---------
__global__ __launch_bounds__(256, 3) void k_attn(const __bf16* __restrict__ Q,
                                                 const __bf16* __restrict__ Kb,
                                                 const __bf16* __restrict__ Vt,
                                                 __bf16* __restrict__ O) {
    __shared__ __align__(16) __bf16 KV[2][8192];         // [buf][K 4096 | V 4096]
    __shared__ __align__(16) __bf16 Pb[4][2][16 * PSTR]; // per-wave, per-group

    int tid  = threadIdx.x;
    int lane = tid & 63, wave = tid >> 6;
    int l16  = lane & 15, quad = lane >> 4;

    int bid = blockIdx.x;
    int xcd = bid & 7;
    int seq = bid >> 3;              // 0..95
    int bh  = xcd * 12 + (seq % 12); // 12 heads per XCD: K/V stays in its L2
    int qt  = seq / 12;              // 0..7, 128 q-rows per block
    int b   = bh / H_, h = bh % H_;

    const __bf16* Qb  = Q  + (size_t)bh * P_ * DV;
    const __bf16* Kbh = Kb + (size_t)bh * P_ * DV;
    const __bf16* Vbh = Vt + (size_t)bh * DV * P_;
    int m0 = qt * 128 + wave * 32;   // 2 groups: rows m0..m0+15, m0+16..m0+31

    bf16x8 a00 = *(const bf16x8*)(Qb + (size_t)(m0 + l16) * DV + quad * 8);
    bf16x8 a01 = *(const bf16x8*)(Qb + (size_t)(m0 + l16) * DV + 32 + quad * 8);
    bf16x8 a10 = *(const bf16x8*)(Qb + (size_t)(m0 + 16 + l16) * DV + quad * 8);
    bf16x8 a11 = *(const bf16x8*)(Qb + (size_t)(m0 + 16 + l16) * DV + 32 + quad * 8);

    int l8 = lane >> 3, q8 = lane & 7;

    bf16x8 ones;
#pragma unroll
    for (int i = 0; i < 8; i++) ones[i] = (__bf16)1.0f;

    __bf16* Pw0 = &Pb[wave][0][0];
    __bf16* Pw1 = &Pb[wave][1][0];
    f32x4 facc0 = {0.f,0.f,0.f,0.f}, facc1 = {0.f,0.f,0.f,0.f};
    f32x4 oacc0[4] = {{0.f,0.f,0.f,0.f},{0.f,0.f,0.f,0.f},{0.f,0.f,0.f,0.f},{0.f,0.f,0.f,0.f}};
    f32x4 oacc1[4] = {{0.f,0.f,0.f,0.f},{0.f,0.f,0.f,0.f},{0.f,0.f,0.f,0.f},{0.f,0.f,0.f,0.f}};
    int swq = l16 & 7;

    // prologue: stage tile 0 into KV[0]
#pragma unroll
    for (int i = 0; i < 2; i++) {
        int t8 = wave * 2 + i;
        int r  = t8 * 8 + l8;
        int j  = q8 ^ (r & 7);
        gload16(Kbh + (size_t)r * DV + j * 8, &KV[0][t8 * 512 + lane * 8]);
        gload16(Vbh + (size_t)r * P_ + j * 8, &KV[0][4096 + t8 * 512 + lane * 8]);
    }

    for (int t = 0; t < 16; t++) {
        int cur = t & 1;
        const __bf16* Ks = &KV[cur][0];
        const __bf16* Vs = &KV[cur][4096];

        // prefetch tile t+1 into the other buffer; counted wait leaves the
        // 4 newest loads in flight across the barrier
        if (t < 15) {
            __bf16* Kd = &KV[cur ^ 1][0];
            int c = (t + 1) * 64;
#pragma unroll
            for (int i = 0; i < 2; i++) {
                int t8 = wave * 2 + i;
                int r  = t8 * 8 + l8;
                int j  = q8 ^ (r & 7);
                gload16(Kbh + (size_t)(c + r) * DV + j * 8, Kd + t8 * 512 + lane * 8);
                gload16(Vbh + (size_t)r * P_ + c + j * 8,  Kd + 4096 + t8 * 512 + lane * 8);
            }
            asm volatile("s_waitcnt vmcnt(4)" ::: "memory");
        } else {
            asm volatile("s_waitcnt vmcnt(0)" ::: "memory");
        }
        __builtin_amdgcn_s_barrier();

        // ---- S^T = K Q^T for both q-groups ----
        f32x4 s0[4], s1[4];
#pragma unroll
        for (int ct = 0; ct < 4; ct++) {
            int R = ct * 16 + l16;
            bf16x8 b0 = *(const bf16x8*)&Ks[R * 64 + ((quad ^ swq) * 8)];
            bf16x8 b1 = *(const bf16x8*)&Ks[R * 64 + (((4 + quad) ^ swq) * 8)];
            f32x4 z0 = {0.f, 0.f, 0.f, 0.f};
            z0 = __builtin_amdgcn_mfma_f32_16x16x32_bf16(b0, a00, z0, 0, 0, 0);
            z0 = __builtin_amdgcn_mfma_f32_16x16x32_bf16(b1, a01, z0, 0, 0, 0);
            s0[ct] = z0;
            f32x4 z1 = {0.f, 0.f, 0.f, 0.f};
            z1 = __builtin_amdgcn_mfma_f32_16x16x32_bf16(b0, a10, z1, 0, 0, 0);
            z1 = __builtin_amdgcn_mfma_f32_16x16x32_bf16(b1, a11, z1, 0, 0, 0);
            s1[ct] = z1;
        }

        // ---- P^T: raw exp2 (Q pre-scaled to log2 domain), b64 writes ----
#pragma unroll
        for (int ct = 0; ct < 4; ct++) {
            bf16x4 pk0, pk1;
#pragma unroll
            for (int r = 0; r < 4; r++) {
                pk0[r] = (__bf16)EX2(s0[ct][r]);
                pk1[r] = (__bf16)EX2(s1[ct][r]);
            }
            *(bf16x4*)&Pw0[l16 * PSTR + ct * 16 + quad * 4] = pk0;
            *(bf16x4*)&Pw1[l16 * PSTR + ct * 16 + quad * 4] = pk1;
        }

        // ---- O^T += V_tile * P^T ; row sums via ones-MFMA ----
#pragma unroll
        for (int ks = 0; ks < 2; ks++) {
            bf16x8 pf0 = *(const bf16x8*)&Pw0[l16 * PSTR + ks * 32 + quad * 8];
            bf16x8 pf1 = *(const bf16x8*)&Pw1[l16 * PSTR + ks * 32 + quad * 8];
            facc0 = __builtin_amdgcn_mfma_f32_16x16x32_bf16(ones, pf0, facc0, 0, 0, 0);
            facc1 = __builtin_amdgcn_mfma_f32_16x16x32_bf16(ones, pf1, facc1, 0, 0, 0);
#pragma unroll
            for (int nt = 0; nt < 4; nt++) {
                int R = nt * 16 + l16;
                bf16x8 av = *(const bf16x8*)&Vs[R * 64 + (((ks * 4 + quad) ^ swq) * 8)];
                oacc0[nt] = __builtin_amdgcn_mfma_f32_16x16x32_bf16(av, pf0, oacc0[nt], 0, 0, 0);
                oacc1[nt] = __builtin_amdgcn_mfma_f32_16x16x32_bf16(av, pf1, oacc1[nt], 0, 0, 0);
            }
        }
        __builtin_amdgcn_s_barrier();
    }

    float inv0 = 1.0f / facc0[0];
    float inv1 = 1.0f / facc1[0];

    {
        int p = m0 + l16;
        __bf16* Orow = O + ((size_t)b * P_ + p) * HD + h * DV;
#pragma unroll
        for (int nt = 0; nt < 4; nt++) {
            bf16x4 o4;
#pragma unroll
            for (int r = 0; r < 4; r++) o4[r] = (__bf16)(oacc0[nt][r] * inv0);
            *(bf16x4*)&Orow[nt * 16 + quad * 4] = o4;
        }
    }
    {
        int p = m0 + 16 + l16;
        __bf16* Orow = O + ((size_t)b * P_ + p) * HD + h * DV;
#pragma unroll
        for (int nt = 0; nt < 4; nt++) {
            bf16x4 o4;
#pragma unroll
            for (int r = 0; r < 4; r++) o4[r] = (__bf16)(oacc1[nt][r] * inv1);
            *(bf16x4*)&Orow[nt * 16 + quad * 4] = o4;
        }
    }
}

extern "C" void kernel_launch(void* const* d_in, const int* in_sizes, int n_in,
                              void* d_out, int out_size, void* d_ws, size_t ws_size,
                              hipStream_t stream) {
    const float* x      = (const float*)d_in[0];
    const float* wqkv   = (const float*)d_in[1];
    const float* wmerge = (const float*)d_in[2];

    char* w = (char*)d_ws;
    __bf16* Xb  = (__bf16*)w;  w += (size_t)B_ * P_ * T_ * 2;
    __bf16* WqT = (__bf16*)w;  w += (size_t)F3 * T_ * 2;
    __bf16* WmT = (__bf16*)w;  w += (size_t)HD * T_ * 2;
    __bf16* Q   = (__bf16*)w;  w += (size_t)B_ * H_ * P_ * DV * 2;
    __bf16* K   = (__bf16*)w;  w += (size_t)B_ * H_ * P_ * DV * 2;
    __bf16* Vt  = (__bf16*)w;  w += (size_t)B_ * H_ * P_ * DV * 2;
    __bf16* O   = (__bf16*)w;

    hipLaunchKernelGGL(k_prep, dim3(768 + 1728 + 576), dim3(256), 0, stream,
                       x, Xb, wqkv, WqT, wmerge, WmT);

    hipLaunchKernelGGL(k_qkv, dim3((B_ * P_ / 128) * (F3 / 128)), dim3(256), 0, stream,
                       Xb, WqT, Q, K, Vt);

    hipLaunchKernelGGL(k_attn, dim3(B_ * H_ * (P_ / 128)), dim3(256), 0, stream,
                       Q, K, Vt, O);

    hipLaunchKernelGGL(k_merge, dim3((B_ * P_ / 128) * (HD / 128)), dim3(256), 0, stream,
                       O, WmT, (float*)d_out);
}